// Round 1
// baseline (641.326 us; speedup 1.0000x reference)
//
#include <hip/hip_runtime.h>
#include <math.h>

#define L_SEQ 2048
#define DMODEL 1024
#define HEADS 16
#define HD 64
#define BATCH 2
#define MROWS (BATCH*L_SEQ)   // 4096
#define KDIM 1024

// ---------------- SGEMM: C = A @ W^T ----------------
// A: (M,K) row-major. W: (N,K) row-major (torch Linear weight). C = A @ W^T.
// mode 1: fused QKV, logical N=3072 over {Wq,Wk,Wv}; epilogue writes head-split
//         layout [(b*H+h)*L + l]*64 + d into C0/C1/C2.
// mode 0: plain C (M x 1024) into C0.
#define BM 128
#define BN 128
#define BKK 8

__global__ __launch_bounds__(256, 2) void sgemm_xwt(
    const float* __restrict__ A,
    const float* __restrict__ W0, const float* __restrict__ W1, const float* __restrict__ W2,
    float* __restrict__ C0, float* __restrict__ C1, float* __restrict__ C2,
    int mode)
{
    __shared__ float As[BKK][BM];
    __shared__ float Bs[BKK][BN];
    const int tid = threadIdx.x;
    const int m0  = blockIdx.x * BM;
    const int n0g = blockIdx.y * BN;

    const float* Wp;
    float* Cq = C0;
    int n0;
    if (mode == 1) {
        const int which = n0g >> 10;          // 0=q 1=k 2=v (128-blocks never cross 1024)
        n0 = n0g & 1023;
        Wp = (which == 0) ? W0 : ((which == 1) ? W1 : W2);
        Cq = (which == 0) ? C0 : ((which == 1) ? C1 : C2);
    } else {
        n0 = n0g;
        Wp = W0;
    }

    const int arow = tid >> 1;        // 0..127
    const int acol = (tid & 1) * 4;   // 0 or 4
    const int tx = tid & 15;          // 0..15 -> cols tx*4 and 64+tx*4
    const int ty = tid >> 4;          // 0..15 -> rows ty*8..ty*8+7

    float acc[8][8];
    #pragma unroll
    for (int i = 0; i < 8; ++i)
        #pragma unroll
        for (int j = 0; j < 8; ++j) acc[i][j] = 0.f;

    for (int k0 = 0; k0 < KDIM; k0 += BKK) {
        float4 av = *(const float4*)&A [(size_t)(m0 + arow)*KDIM + k0 + acol];
        float4 bv = *(const float4*)&Wp[(size_t)(n0 + arow)*KDIM + k0 + acol];
        __syncthreads();
        As[acol+0][arow] = av.x; As[acol+1][arow] = av.y;
        As[acol+2][arow] = av.z; As[acol+3][arow] = av.w;
        Bs[acol+0][arow] = bv.x; Bs[acol+1][arow] = bv.y;
        Bs[acol+2][arow] = bv.z; Bs[acol+3][arow] = bv.w;
        __syncthreads();
        #pragma unroll
        for (int kk = 0; kk < BKK; ++kk) {
            float a[8], b[8];
            *(float4*)&a[0] = *(const float4*)&As[kk][ty*8];
            *(float4*)&a[4] = *(const float4*)&As[kk][ty*8+4];
            *(float4*)&b[0] = *(const float4*)&Bs[kk][tx*4];
            *(float4*)&b[4] = *(const float4*)&Bs[kk][64 + tx*4];
            #pragma unroll
            for (int im = 0; im < 8; ++im)
                #pragma unroll
                for (int in = 0; in < 8; ++in)
                    acc[im][in] = fmaf(a[im], b[in], acc[im][in]);
        }
    }

    #pragma unroll
    for (int im = 0; im < 8; ++im) {
        const int m = m0 + ty*8 + im;
        #pragma unroll
        for (int half = 0; half < 2; ++half) {
            const int col = half*64 + tx*4;
            float4 val = make_float4(acc[im][half*4+0], acc[im][half*4+1],
                                     acc[im][half*4+2], acc[im][half*4+3]);
            if (mode == 1) {
                const int oo = n0 + col;
                const int h = oo >> 6, d = oo & 63;
                const int b = m >> 11, l = m & (L_SEQ - 1);
                *(float4*)&Cq[(((size_t)(b*HEADS + h)*L_SEQ) + l)*HD + d] = val;
            } else {
                *(float4*)&C0[(size_t)m*DMODEL + n0 + col] = val;
            }
        }
    }
}

// ---------------- k_mean over L per (b,h) ----------------
__global__ __launch_bounds__(256) void kmean_kernel(
    const float* __restrict__ k, float* __restrict__ kmean)
{
    __shared__ float part[4][64];
    const int bh = blockIdx.x;
    const int tid = threadIdx.x;
    const int d = tid & 63, pr = tid >> 6;
    const float* kp = k + (size_t)bh * L_SEQ * HD;
    float s = 0.f;
    for (int l = pr*512; l < pr*512 + 512; ++l)
        s += kp[(size_t)l*HD + d];
    part[pr][d] = s;
    __syncthreads();
    if (tid < 64) {
        float t = part[0][tid] + part[1][tid] + part[2][tid] + part[3][tid];
        kmean[bh*HD + tid] = t * (1.f / (float)L_SEQ);
    }
}

// ---------------- windowed attention ----------------
// One block = one (b,h) x 32 consecutive queries. 4 waves, 8 queries/wave.
// Keys/values j in [q0-63, q0+31] staged in LDS (95 used rows, 96 staged).
#define QT 32
#define KR 96

__global__ __launch_bounds__(256, 2) void attn_kernel(
    const float* __restrict__ q, const float* __restrict__ k,
    const float* __restrict__ v, const float* __restrict__ kmean,
    const float* __restrict__ g_sep, const float* __restrict__ g_align,
    const float* __restrict__ g_coh, float* __restrict__ out)
{
    __shared__ float ks_t[HD][KR+1];   // [d][r], stride 97 -> conflict-free both ways
    __shared__ float vs[KR][HD];       // [r][d]
    __shared__ float qs[QT][HD];
    __shared__ float ps[4][64];

    const int tid = threadIdx.x;
    const int nqt = L_SEQ / QT;             // 64
    const int bh = blockIdx.x / nqt;        // 0..31
    const int qt = blockIdx.x % nqt;
    const int q0 = qt * QT;
    const int j0 = q0 - 63;

    const float* qbh = q + (size_t)bh * L_SEQ * HD;
    const float* kbh = k + (size_t)bh * L_SEQ * HD;
    const float* vbh = v + (size_t)bh * L_SEQ * HD;

    // stage K (transposed) and V
    for (int idx = tid; idx < KR*16; idx += 256) {
        const int r = idx >> 4, f4 = (idx & 15) * 4;
        int j = j0 + r;
        j = j < 0 ? 0 : (j > L_SEQ-1 ? L_SEQ-1 : j);
        float4 kv4 = *(const float4*)&kbh[(size_t)j*HD + f4];
        float4 vv4 = *(const float4*)&vbh[(size_t)j*HD + f4];
        ks_t[f4+0][r] = kv4.x; ks_t[f4+1][r] = kv4.y;
        ks_t[f4+2][r] = kv4.z; ks_t[f4+3][r] = kv4.w;
        *(float4*)&vs[r][f4] = vv4;
    }
    // stage Q
    for (int idx = tid; idx < QT*16; idx += 256) {
        const int r = idx >> 4, f4 = (idx & 15) * 4;
        *(float4*)&qs[r][f4] = *(const float4*)&qbh[(size_t)(q0 + r)*HD + f4];
    }

    const int w = tid >> 6, lane = tid & 63;
    const float km    = kmean[bh*HD + lane];
    const float sep   = g_sep[0];
    const float align = g_align[0];
    const float coh   = g_coh[0];
    __syncthreads();

    const int b = bh >> 4, h = bh & (HEADS - 1);

    for (int qq = 0; qq < QT/4; ++qq) {
        const int iq = w * (QT/4) + qq;
        const int i = q0 + iq;

        // (a) row mean of raw scores: q_i . k_mean / 8   (lane = d)
        float mv = qs[iq][lane] * km;
        #pragma unroll
        for (int off = 32; off; off >>= 1) mv += __shfl_xor(mv, off, 64);
        const float mean_i = mv * 0.125f;

        // (b) windowed raw score (lane = jj, key j = i-63+jj, LDS row iq+jj)
        float s = 0.f;
        #pragma unroll
        for (int d = 0; d < HD; ++d)
            s = fmaf(qs[iq][d], ks_t[d][iq + lane], s);
        s *= 0.125f;

        // (c) Reynolds adjustments
        const float sig = 1.f / (1.f + __expf(-s));
        float adj = s * (1.f + align) - sep * sig * sig - coh * fabsf(s - mean_i);
        const int jg = i - 63 + lane;
        if (jg < 0) adj = -1e30f;

        // (d) softmax over the 64-wide window (wave butterfly)
        float mmax = adj;
        #pragma unroll
        for (int off = 32; off; off >>= 1) mmax = fmaxf(mmax, __shfl_xor(mmax, off, 64));
        const float p = __expf(adj - mmax);
        float lsum = p;
        #pragma unroll
        for (int off = 32; off; off >>= 1) lsum += __shfl_xor(lsum, off, 64);
        ps[w][lane] = p;

        // (e) PV (lane = d)
        float accv = 0.f;
        #pragma unroll
        for (int jj = 0; jj < 64; ++jj)
            accv = fmaf(ps[w][jj], vs[iq + jj][lane], accv);
        accv /= lsum;

        out[((size_t)(b*L_SEQ + i))*DMODEL + h*HD + lane] = accv;
    }
}

extern "C" void kernel_launch(void* const* d_in, const int* in_sizes, int n_in,
                              void* d_out, int out_size, void* d_ws, size_t ws_size,
                              hipStream_t stream)
{
    (void)in_sizes; (void)n_in; (void)out_size; (void)ws_size;
    const float* x     = (const float*)d_in[0];
    const float* Wq    = (const float*)d_in[1];
    const float* Wk    = (const float*)d_in[2];
    const float* Wv    = (const float*)d_in[3];
    const float* Wo    = (const float*)d_in[4];
    const float* g_sep   = (const float*)d_in[5];
    const float* g_align = (const float*)d_in[6];
    const float* g_coh   = (const float*)d_in[7];
    float* out = (float*)d_out;

    float* ws = (float*)d_ws;
    const size_t per = (size_t)BATCH*HEADS*L_SEQ*HD;   // 4,194,304 floats
    float* q_ws = ws;
    float* k_ws = q_ws + per;
    float* v_ws = k_ws + per;
    float* kmean_ws = v_ws + per;
    float* att_ws = kmean_ws + BATCH*HEADS*HD;

    dim3 blk(256);
    // fused QKV projection, head-split epilogue
    sgemm_xwt<<<dim3(MROWS/BM, 3*DMODEL/BN), blk, 0, stream>>>(
        x, Wq, Wk, Wv, q_ws, k_ws, v_ws, 1);
    // k_mean per (b,h)
    kmean_kernel<<<dim3(BATCH*HEADS), blk, 0, stream>>>(k_ws, kmean_ws);
    // windowed attention with Reynolds rules
    attn_kernel<<<dim3(BATCH*HEADS*(L_SEQ/QT)), blk, 0, stream>>>(
        q_ws, k_ws, v_ws, kmean_ws, g_sep, g_align, g_coh, att_ws);
    // output projection straight into d_out
    sgemm_xwt<<<dim3(MROWS/BM, DMODEL/BN), blk, 0, stream>>>(
        att_ws, Wo, nullptr, nullptr, out, nullptr, nullptr, 0);
}

// Round 2
// 272.953 us; speedup vs baseline: 2.3496x; 2.3496x over previous
//
#include <hip/hip_runtime.h>
#include <math.h>

#define L_SEQ 2048
#define DMODEL 1024
#define HEADS 16
#define HD 64
#define BATCH 2
#define MROWS (BATCH*L_SEQ)   // 4096
#define KDIM 1024

typedef short bfrag8 __attribute__((ext_vector_type(8)));   // 8 bf16 = 4 VGPRs
typedef float f32x4f __attribute__((ext_vector_type(4)));

__device__ __forceinline__ unsigned short f2bf(float f) {
    unsigned u = __float_as_uint(f);
    unsigned r = u + 0x7FFFu + ((u >> 16) & 1u);   // RNE
    return (unsigned short)(r >> 16);
}

// ---------------- fp32 -> bf16 convert (x + 4 weights) ----------------
// grid: 8192 blocks x 256 thr; each thread converts 4 floats.
__global__ __launch_bounds__(256) void convert_bf16(
    const float* __restrict__ x, const float* __restrict__ wq,
    const float* __restrict__ wk, const float* __restrict__ wv,
    const float* __restrict__ wo,
    unsigned short* __restrict__ xb, unsigned short* __restrict__ qb,
    unsigned short* __restrict__ kb, unsigned short* __restrict__ vb,
    unsigned short* __restrict__ ob)
{
    const int bid = blockIdx.x;
    const float* src; unsigned short* dst; size_t base;
    if (bid < 4096) { src = x; dst = xb; base = (size_t)bid * 1024; }
    else {
        const int r = bid - 4096; const int w = r >> 10; const int off = r & 1023;
        src = (w==0) ? wq : (w==1) ? wk : (w==2) ? wv : wo;
        dst = (w==0) ? qb : (w==1) ? kb : (w==2) ? vb : ob;
        base = (size_t)off * 1024;
    }
    const size_t idx = base + (size_t)threadIdx.x * 4;
    float4 v = *(const float4*)&src[idx];
    ushort4 o;
    o.x = f2bf(v.x); o.y = f2bf(v.y); o.z = f2bf(v.z); o.w = f2bf(v.w);
    *(ushort4*)&dst[idx] = o;
}

// ---------------- MFMA bf16 GEMM: C = A @ W^T ----------------
// A: (M,1024) bf16 row-major. W: (N,1024) bf16 row-major. C fp32.
// 128x128 block tile, BK=32, 4 waves in 2x2, 64x64 wave tile of 4x4 16x16x32 MFMAs.
// mode 1: N=3072 logical over {Wq,Wk,Wv}; epilogue head-splits into C0/C1/C2
//         at [(b*H+h)*L + l]*64 + d.  mode 0: plain (M,1024) into C0.
#define GBK 32

__global__ void mfma_gemm(
    const unsigned short* __restrict__ A,
    const unsigned short* __restrict__ W0, const unsigned short* __restrict__ W1,
    const unsigned short* __restrict__ W2,
    float* __restrict__ C0, float* __restrict__ C1, float* __restrict__ C2,
    int mode)
{
    __shared__ short As[128*GBK];   // [row][k] row-major, NO padding (global_load_lds)
    __shared__ short Bs[128*GBK];

    const int tid  = threadIdx.x;
    const int wave = tid >> 6, lane = tid & 63;
    const int m0   = blockIdx.x * 128;
    const int n0g  = blockIdx.y * 128;

    const unsigned short* Wp; float* Cp; int n0;
    if (mode == 1) {
        const int which = n0g >> 10;            // uniform per block
        n0 = n0g & 1023;
        Wp = (which==0) ? W0 : (which==1) ? W1 : W2;
        Cp = (which==0) ? C0 : (which==1) ? C1 : C2;
    } else { n0 = n0g; Wp = W0; Cp = C0; }

    const int quad = lane >> 4, lm = lane & 15;
    const int wm = wave >> 1, wn = wave & 1;

    f32x4f acc[4][4] = {};

    // staging: each wave stages 1024 elems of each tile per issue-pair.
    // issue i in {0,1}: wave-uniform LDS elem base = wave*1024 + i*512,
    // lane covers elems base+lane*8 .. +7 (16B each -> global_load_lds_dwordx4).
    const int ebase0 = wave * 1024;

    for (int k0 = 0; k0 < KDIM; k0 += GBK) {
        __syncthreads();   // previous iter's ds_reads done before overwrite
        #pragma unroll
        for (int i = 0; i < 2; ++i) {
            const int ebase = ebase0 + i * 512;
            const int e = ebase + lane * 8;
            const int row = e >> 5, col = e & 31;
            __builtin_amdgcn_global_load_lds(
                (const __attribute__((address_space(1))) void*)(A + (size_t)(m0 + row) * KDIM + k0 + col),
                (__attribute__((address_space(3))) void*)(&As[ebase]), 16, 0, 0);
            __builtin_amdgcn_global_load_lds(
                (const __attribute__((address_space(1))) void*)(Wp + (size_t)(n0 + row) * KDIM + k0 + col),
                (__attribute__((address_space(3))) void*)(&Bs[ebase]), 16, 0, 0);
        }
        __syncthreads();   // drains vmcnt -> LDS visible

        bfrag8 af[4], bf[4];
        #pragma unroll
        for (int t = 0; t < 4; ++t) {
            af[t] = *(const bfrag8*)&As[(wm*64 + t*16 + lm)*GBK + quad*8];
            bf[t] = *(const bfrag8*)&Bs[(wn*64 + t*16 + lm)*GBK + quad*8];
        }
        #pragma unroll
        for (int mt = 0; mt < 4; ++mt)
            #pragma unroll
            for (int nt = 0; nt < 4; ++nt)
                acc[mt][nt] = __builtin_amdgcn_mfma_f32_16x16x32_bf16(
                    af[mt], bf[nt], acc[mt][nt], 0, 0, 0);
    }

    // epilogue: C/D layout col=lane&15, row=quad*4+reg  [m89-verified]
    #pragma unroll
    for (int mt = 0; mt < 4; ++mt) {
        #pragma unroll
        for (int nt = 0; nt < 4; ++nt) {
            const int gn = n0 + wn*64 + nt*16 + lm;
            if (mode == 1) {
                const int h = gn >> 6, d = gn & 63;
                #pragma unroll
                for (int r = 0; r < 4; ++r) {
                    const int gm = m0 + wm*64 + mt*16 + quad*4 + r;
                    const int b = gm >> 11, l = gm & (L_SEQ-1);
                    Cp[(((size_t)(b*HEADS + h) * L_SEQ) + l) * HD + d] = acc[mt][nt][r];
                }
            } else {
                #pragma unroll
                for (int r = 0; r < 4; ++r) {
                    const int gm = m0 + wm*64 + mt*16 + quad*4 + r;
                    Cp[(size_t)gm * DMODEL + gn] = acc[mt][nt][r];
                }
            }
        }
    }
}

// ---------------- x partial column-sums: (b, chunk of 64 rows) ----------------
__global__ __launch_bounds__(256) void xpart_kernel(
    const float* __restrict__ x, float* __restrict__ xpart)
{
    const int b = blockIdx.x >> 5, ch = blockIdx.x & 31;
    const int c4 = threadIdx.x * 4;
    float4 s = make_float4(0.f, 0.f, 0.f, 0.f);
    const float* xp = x + ((size_t)b * L_SEQ + ch * 64) * DMODEL + c4;
    for (int r = 0; r < 64; ++r) {
        float4 v = *(const float4*)&xp[(size_t)r * DMODEL];
        s.x += v.x; s.y += v.y; s.z += v.z; s.w += v.w;
    }
    *(float4*)&xpart[(size_t)blockIdx.x * DMODEL + c4] = s;
}

// ---------------- kmean via linearity: kmean[b,h,:] = xmean[b] @ Wk_head^T ----
// grid 32 blocks (b,h) x 64 threads (d). fp32 exact path.
__global__ __launch_bounds__(64) void kmean_kernel(
    const float* __restrict__ xpart, const float* __restrict__ Wk,
    float* __restrict__ kmean)
{
    __shared__ float xm[DMODEL];
    const int b = blockIdx.x >> 4, h = blockIdx.x & 15;
    const int t = threadIdx.x;
    for (int c = t; c < DMODEL; c += 64) {
        float s = 0.f;
        #pragma unroll 8
        for (int ch = 0; ch < 32; ++ch) s += xpart[(size_t)(b*32 + ch) * DMODEL + c];
        xm[c] = s * (1.f / (float)L_SEQ);
    }
    __syncthreads();
    const float* wr = Wk + (size_t)(h * HD + t) * KDIM;
    float dot = 0.f;
    for (int c = 0; c < KDIM; c += 4) {
        float4 a = *(const float4*)&xm[c];
        float4 w = *(const float4*)&wr[c];
        dot = fmaf(a.x, w.x, fmaf(a.y, w.y, fmaf(a.z, w.z, fmaf(a.w, w.w, dot))));
    }
    kmean[(size_t)(b * HEADS + h) * HD + t] = dot;   // mean_j k_j
}

// ---------------- windowed attention (fp32 in, bf16 out) ----------------
#define QT 32
#define KR 96

__global__ __launch_bounds__(256, 2) void attn_kernel(
    const float* __restrict__ q, const float* __restrict__ k,
    const float* __restrict__ v, const float* __restrict__ kmean,
    const float* __restrict__ g_sep, const float* __restrict__ g_align,
    const float* __restrict__ g_coh, unsigned short* __restrict__ out)
{
    __shared__ float ks_t[HD][KR+1];   // [d][r], stride 97 -> conflict-free
    __shared__ float vs[KR][HD];
    __shared__ float qs[QT][HD];
    __shared__ float ps[4][64];

    const int tid = threadIdx.x;
    const int nqt = L_SEQ / QT;
    const int bh = blockIdx.x / nqt;
    const int qt = blockIdx.x % nqt;
    const int q0 = qt * QT;
    const int j0 = q0 - 63;

    const float* qbh = q + (size_t)bh * L_SEQ * HD;
    const float* kbh = k + (size_t)bh * L_SEQ * HD;
    const float* vbh = v + (size_t)bh * L_SEQ * HD;

    for (int idx = tid; idx < KR*16; idx += 256) {
        const int r = idx >> 4, f4 = (idx & 15) * 4;
        int j = j0 + r;
        j = j < 0 ? 0 : (j > L_SEQ-1 ? L_SEQ-1 : j);
        float4 kv4 = *(const float4*)&kbh[(size_t)j*HD + f4];
        float4 vv4 = *(const float4*)&vbh[(size_t)j*HD + f4];
        ks_t[f4+0][r] = kv4.x; ks_t[f4+1][r] = kv4.y;
        ks_t[f4+2][r] = kv4.z; ks_t[f4+3][r] = kv4.w;
        *(float4*)&vs[r][f4] = vv4;
    }
    for (int idx = tid; idx < QT*16; idx += 256) {
        const int r = idx >> 4, f4 = (idx & 15) * 4;
        *(float4*)&qs[r][f4] = *(const float4*)&qbh[(size_t)(q0 + r)*HD + f4];
    }

    const int w = tid >> 6, lane = tid & 63;
    const float km    = kmean[bh*HD + lane];
    const float sep   = g_sep[0];
    const float align = g_align[0];
    const float coh   = g_coh[0];
    __syncthreads();

    const int b = bh >> 4, h = bh & (HEADS - 1);

    for (int qq = 0; qq < QT/4; ++qq) {
        const int iq = w * (QT/4) + qq;
        const int i = q0 + iq;

        float mv = qs[iq][lane] * km;
        #pragma unroll
        for (int off = 32; off; off >>= 1) mv += __shfl_xor(mv, off, 64);
        const float mean_i = mv * 0.125f;

        float s = 0.f;
        #pragma unroll
        for (int d = 0; d < HD; ++d)
            s = fmaf(qs[iq][d], ks_t[d][iq + lane], s);
        s *= 0.125f;

        const float sig = 1.f / (1.f + __expf(-s));
        float adj = s * (1.f + align) - sep * sig * sig - coh * fabsf(s - mean_i);
        const int jg = i - 63 + lane;
        if (jg < 0) adj = -1e30f;

        float mmax = adj;
        #pragma unroll
        for (int off = 32; off; off >>= 1) mmax = fmaxf(mmax, __shfl_xor(mmax, off, 64));
        const float p = __expf(adj - mmax);
        float lsum = p;
        #pragma unroll
        for (int off = 32; off; off >>= 1) lsum += __shfl_xor(lsum, off, 64);
        ps[w][lane] = p;

        float accv = 0.f;
        #pragma unroll
        for (int jj = 0; jj < 64; ++jj)
            accv = fmaf(ps[w][jj], vs[iq + jj][lane], accv);
        accv /= lsum;

        out[((size_t)(b*L_SEQ + i))*DMODEL + h*HD + lane] = f2bf(accv);
    }
}

extern "C" void kernel_launch(void* const* d_in, const int* in_sizes, int n_in,
                              void* d_out, int out_size, void* d_ws, size_t ws_size,
                              hipStream_t stream)
{
    (void)in_sizes; (void)n_in; (void)out_size; (void)ws_size;
    const float* x     = (const float*)d_in[0];
    const float* Wq    = (const float*)d_in[1];
    const float* Wk    = (const float*)d_in[2];
    const float* Wv    = (const float*)d_in[3];
    const float* Wo    = (const float*)d_in[4];
    const float* g_sep   = (const float*)d_in[5];
    const float* g_align = (const float*)d_in[6];
    const float* g_coh   = (const float*)d_in[7];
    float* out = (float*)d_out;

    // workspace layout (72.3 MB total)
    float* f = (float*)d_ws;
    const size_t per = (size_t)BATCH*HEADS*L_SEQ*HD;   // 4 Mi floats
    float* q_ws = f;
    float* k_ws = q_ws + per;
    float* v_ws = k_ws + per;
    float* kmean_ws = v_ws + per;                 // 2048
    float* xpart_ws = kmean_ws + 2048;            // 65536
    unsigned short* xb  = (unsigned short*)(xpart_ws + 65536);  // 4 Mi bf16
    unsigned short* wqb = xb  + per;              // 1 Mi each
    unsigned short* wkb = wqb + (size_t)DMODEL*KDIM;
    unsigned short* wvb = wkb + (size_t)DMODEL*KDIM;
    unsigned short* wob = wvb + (size_t)DMODEL*KDIM;
    unsigned short* attb = wob + (size_t)DMODEL*KDIM;  // 4 Mi bf16

    convert_bf16<<<dim3(8192), dim3(256), 0, stream>>>(
        x, Wq, Wk, Wv, Wo, xb, wqb, wkb, wvb, wob);
    xpart_kernel<<<dim3(64), dim3(256), 0, stream>>>(x, xpart_ws);
    mfma_gemm<<<dim3(MROWS/128, 3*DMODEL/128), dim3(256), 0, stream>>>(
        xb, wqb, wkb, wvb, q_ws, k_ws, v_ws, 1);
    kmean_kernel<<<dim3(BATCH*HEADS), dim3(64), 0, stream>>>(xpart_ws, Wk, kmean_ws);
    attn_kernel<<<dim3(BATCH*HEADS*(L_SEQ/QT)), dim3(256), 0, stream>>>(
        q_ws, k_ws, v_ws, kmean_ws, g_sep, g_align, g_coh, attb);
    mfma_gemm<<<dim3(MROWS/128, DMODEL/128), dim3(256), 0, stream>>>(
        attb, wob, nullptr, nullptr, out, nullptr, nullptr, 0);
}

// Round 3
// 208.501 us; speedup vs baseline: 3.0759x; 1.3091x over previous
//
#include <hip/hip_runtime.h>
#include <math.h>

#define L_SEQ 2048
#define DMODEL 1024
#define HEADS 16
#define HD 64
#define BATCH 2
#define MROWS (BATCH*L_SEQ)   // 4096
#define KDIM 1024

typedef short bfrag8 __attribute__((ext_vector_type(8)));   // 8 bf16 = 4 VGPRs
typedef float f32x4f __attribute__((ext_vector_type(4)));

__device__ __forceinline__ unsigned short f2bf(float f) {
    unsigned u = __float_as_uint(f);
    unsigned r = u + 0x7FFFu + ((u >> 16) & 1u);   // RNE
    return (unsigned short)(r >> 16);
}
__device__ __forceinline__ float bf2f(short h) {
    return __uint_as_float(((unsigned)(unsigned short)h) << 16);
}

// ------- convert x+weights to bf16; also x column partial sums (for kmean) ----
// blocks 0..63: x rows [bid*64, bid*64+64): convert + column sums -> xpart[bid].
// blocks 64..4159: weight rows.
__global__ __launch_bounds__(256) void convert_and_stats(
    const float* __restrict__ x, const float* __restrict__ wq,
    const float* __restrict__ wk, const float* __restrict__ wv,
    const float* __restrict__ wo,
    unsigned short* __restrict__ xb, unsigned short* __restrict__ qwb,
    unsigned short* __restrict__ kwb, unsigned short* __restrict__ vwb,
    unsigned short* __restrict__ owb, float* __restrict__ xpart)
{
    const int bid = blockIdx.x, t = threadIdx.x;
    if (bid < 64) {
        const size_t rbase = (size_t)bid * 64;
        const int c4 = t * 4;
        float4 s = make_float4(0.f, 0.f, 0.f, 0.f);
        for (int r = 0; r < 64; ++r) {
            const size_t off = (rbase + r) * DMODEL + c4;
            float4 v = *(const float4*)&x[off];
            s.x += v.x; s.y += v.y; s.z += v.z; s.w += v.w;
            ushort4 o; o.x = f2bf(v.x); o.y = f2bf(v.y); o.z = f2bf(v.z); o.w = f2bf(v.w);
            *(ushort4*)&xb[off] = o;
        }
        *(float4*)&xpart[(size_t)bid * DMODEL + c4] = s;
    } else {
        const int r = bid - 64;
        const int w = r >> 10, off = r & 1023;
        const float* src = (w==0) ? wq : (w==1) ? wk : (w==2) ? wv : wo;
        unsigned short* dst = (w==0) ? qwb : (w==1) ? kwb : (w==2) ? vwb : owb;
        const size_t idx = (size_t)off * 1024 + (size_t)t * 4;
        float4 v = *(const float4*)&src[idx];
        ushort4 o; o.x = f2bf(v.x); o.y = f2bf(v.y); o.z = f2bf(v.z); o.w = f2bf(v.w);
        *(ushort4*)&dst[idx] = o;
    }
}

// ---------------- MFMA bf16 GEMM: C = A @ W^T ----------------
// MODE 1: N=3072 logical over {Wq,Wk,Wv}; head-split bf16 epilogue into C0/C1/C2
//         at [(b*H+h)*L + l]*64 + d.   MODE 0: plain fp32 (M,1024) into C0.
#define GBK 32

template<int MODE>
__global__ void mfma_gemm(
    const unsigned short* __restrict__ A,
    const unsigned short* __restrict__ W0, const unsigned short* __restrict__ W1,
    const unsigned short* __restrict__ W2,
    void* __restrict__ C0v, void* __restrict__ C1v, void* __restrict__ C2v)
{
    __shared__ short As[128*GBK];   // [row][k] row-major, NO padding (global_load_lds)
    __shared__ short Bs[128*GBK];

    const int tid  = threadIdx.x;
    const int wave = tid >> 6, lane = tid & 63;
    const int m0   = blockIdx.x * 128;
    const int n0g  = blockIdx.y * 128;

    const unsigned short* Wp; int n0; int which = 0;
    if (MODE == 1) {
        which = n0g >> 10;                      // uniform per block
        n0 = n0g & 1023;
        Wp = (which==0) ? W0 : (which==1) ? W1 : W2;
    } else { n0 = n0g; Wp = W0; }

    const int quad = lane >> 4, lm = lane & 15;
    const int wm = wave >> 1, wn = wave & 1;

    f32x4f acc[4][4] = {};

    const int ebase0 = wave * 1024;

    for (int k0 = 0; k0 < KDIM; k0 += GBK) {
        __syncthreads();
        #pragma unroll
        for (int i = 0; i < 2; ++i) {
            const int ebase = ebase0 + i * 512;
            const int e = ebase + lane * 8;
            const int row = e >> 5, col = e & 31;
            __builtin_amdgcn_global_load_lds(
                (const __attribute__((address_space(1))) void*)(A + (size_t)(m0 + row) * KDIM + k0 + col),
                (__attribute__((address_space(3))) void*)(&As[ebase]), 16, 0, 0);
            __builtin_amdgcn_global_load_lds(
                (const __attribute__((address_space(1))) void*)(Wp + (size_t)(n0 + row) * KDIM + k0 + col),
                (__attribute__((address_space(3))) void*)(&Bs[ebase]), 16, 0, 0);
        }
        __syncthreads();

        bfrag8 af[4], bf[4];
        #pragma unroll
        for (int t = 0; t < 4; ++t) {
            af[t] = *(const bfrag8*)&As[(wm*64 + t*16 + lm)*GBK + quad*8];
            bf[t] = *(const bfrag8*)&Bs[(wn*64 + t*16 + lm)*GBK + quad*8];
        }
        #pragma unroll
        for (int mt = 0; mt < 4; ++mt)
            #pragma unroll
            for (int nt = 0; nt < 4; ++nt)
                acc[mt][nt] = __builtin_amdgcn_mfma_f32_16x16x32_bf16(
                    af[mt], bf[nt], acc[mt][nt], 0, 0, 0);
    }

    // epilogue: C/D layout col=lane&15, row=quad*4+reg
    if (MODE == 1) {
        unsigned short* Cp = (unsigned short*)((which==0) ? C0v : (which==1) ? C1v : C2v);
        #pragma unroll
        for (int mt = 0; mt < 4; ++mt)
            #pragma unroll
            for (int nt = 0; nt < 4; ++nt) {
                const int gn = n0 + wn*64 + nt*16 + lm;
                const int h = gn >> 6, d = gn & 63;
                #pragma unroll
                for (int r = 0; r < 4; ++r) {
                    const int gm = m0 + wm*64 + mt*16 + quad*4 + r;
                    const int b = gm >> 11, l = gm & (L_SEQ-1);
                    Cp[(((size_t)(b*HEADS + h) * L_SEQ) + l) * HD + d] = f2bf(acc[mt][nt][r]);
                }
            }
    } else {
        float* Cp = (float*)C0v;
        #pragma unroll
        for (int mt = 0; mt < 4; ++mt)
            #pragma unroll
            for (int nt = 0; nt < 4; ++nt) {
                const int gn = n0 + wn*64 + nt*16 + lm;
                #pragma unroll
                for (int r = 0; r < 4; ++r) {
                    const int gm = m0 + wm*64 + mt*16 + quad*4 + r;
                    Cp[(size_t)gm * DMODEL + gn] = acc[mt][nt][r];
                }
            }
    }
}

// ---------------- kmean via linearity: kmean[b,h,:] = (mean_l x) @ Wk_head^T --
__global__ __launch_bounds__(64) void kmean_kernel(
    const float* __restrict__ xpart, const float* __restrict__ Wk,
    float* __restrict__ kmean)
{
    __shared__ float xm[DMODEL];
    const int b = blockIdx.x >> 4, h = blockIdx.x & 15;
    const int t = threadIdx.x;
    for (int c = t; c < DMODEL; c += 64) {
        float s = 0.f;
        #pragma unroll 8
        for (int ch = 0; ch < 32; ++ch) s += xpart[(size_t)(b*32 + ch) * DMODEL + c];
        xm[c] = s * (1.f / (float)L_SEQ);
    }
    __syncthreads();
    const float* wr = Wk + (size_t)(h * HD + t) * KDIM;
    float dot = 0.f;
    for (int c = 0; c < KDIM; c += 4) {
        float4 a = *(const float4*)&xm[c];
        float4 w = *(const float4*)&wr[c];
        dot = fmaf(a.x, w.x, fmaf(a.y, w.y, fmaf(a.z, w.z, fmaf(a.w, w.w, dot))));
    }
    kmean[(size_t)(b * HEADS + h) * HD + t] = dot;
}

// ---------------- MFMA windowed attention ----------------
// Block = one (b,h) x 64 queries; 4 waves x 16 queries.
// Wave w: QK^T over 5 key-tiles (rel keys [16w, 16w+80)) via 16x16x32 bf16 MFMA,
// softmax in C-layout regs, P->LDS (bf16, cols 80..95 zeroed), PV via MFMA with
// V^T staged in LDS.
#define QT 64
#define KROWS 128
#define VROWS 144
#define KS_STRIDE 72    // shorts; 144 B rows (16B-aligned), 2-way banks = free
#define VT_STRIDE 152   // shorts; 304 B rows
#define P_STRIDE 104    // shorts; 208 B rows

__global__ __launch_bounds__(256, 3) void attn_kernel(
    const unsigned short* __restrict__ qb, const unsigned short* __restrict__ kb,
    const unsigned short* __restrict__ vb, const float* __restrict__ kmean,
    const float* __restrict__ g_sep, const float* __restrict__ g_align,
    const float* __restrict__ g_coh, unsigned short* __restrict__ out)
{
    __shared__ unsigned short ks[KROWS * KS_STRIDE];
    __shared__ unsigned short vst[HD * VT_STRIDE];
    __shared__ unsigned short pl[QT * P_STRIDE];
    __shared__ float smean[QT];
    __shared__ float km_s[HD];

    const int tid = threadIdx.x;
    const int bh = blockIdx.x >> 5;        // L/QT = 32 tiles per (b,h)
    const int qt = blockIdx.x & 31;
    const int q0 = qt * QT;
    const int j0 = q0 - 63;

    const unsigned short* kbh = kb + (size_t)bh * L_SEQ * HD;
    const unsigned short* vbh = vb + (size_t)bh * L_SEQ * HD;

    if (tid < HD) km_s[tid] = kmean[bh * HD + tid];

    // stage K rows rel 0..127 (clamped), row-major
    for (int idx = tid; idx < KROWS * 8; idx += 256) {
        const int r = idx & (KROWS - 1);
        const int c8 = idx >> 7;
        int j = j0 + r; j = j < 0 ? 0 : (j >= L_SEQ ? L_SEQ - 1 : j);
        bfrag8 d = *(const bfrag8*)&kbh[(size_t)j * HD + c8 * 8];
        *(bfrag8*)&ks[r * KS_STRIDE + c8 * 8] = d;
    }
    // stage V transposed, rel 0..143 (rel>=128 only ever multiplied by zero-P,
    // but must be finite -> stage real clamped data)
    for (int idx = tid; idx < VROWS * 8; idx += 256) {
        const int r = idx % VROWS;
        const int c8 = idx / VROWS;
        int j = j0 + r; j = j < 0 ? 0 : (j >= L_SEQ ? L_SEQ - 1 : j);
        bfrag8 d = *(const bfrag8*)&vbh[(size_t)j * HD + c8 * 8];
        #pragma unroll
        for (int e = 0; e < 8; ++e)
            vst[(c8 * 8 + e) * VT_STRIDE + r] = (unsigned short)d[e];
    }

    const int w = tid >> 6, lane = tid & 63;
    const int quad = lane >> 4, lm = lane & 15;
    const float sep = g_sep[0], align = g_align[0], coh = g_coh[0];

    // Q a-frags straight from global (A[m=lane&15][k=quad*8+j], ksteps 0/1)
    const unsigned short* qrow =
        qb + ((size_t)bh * L_SEQ + q0 + w*16 + lm) * HD + quad * 8;
    bfrag8 qa0 = *(const bfrag8*)qrow;
    bfrag8 qa1 = *(const bfrag8*)(qrow + 32);

    __syncthreads();

    // per-query q . kmean (cohesion mean), via the a-frags
    float part = 0.f;
    #pragma unroll
    for (int j = 0; j < 8; ++j)
        part += bf2f(qa0[j]) * km_s[quad*8 + j] + bf2f(qa1[j]) * km_s[32 + quad*8 + j];
    part += __shfl_xor(part, 16, 64);
    part += __shfl_xor(part, 32, 64);
    if (quad == 0) smean[w*16 + lm] = part;

    // QK^T: 5 tiles x 2 MFMAs
    f32x4f sacc[5];
    #pragma unroll
    for (int t = 0; t < 5; ++t) {
        const int krow = w*16 + t*16 + lm;
        bfrag8 b0 = *(const bfrag8*)&ks[krow * KS_STRIDE + quad*8];
        bfrag8 b1 = *(const bfrag8*)&ks[krow * KS_STRIDE + 32 + quad*8];
        f32x4f z = {0.f, 0.f, 0.f, 0.f};
        z = __builtin_amdgcn_mfma_f32_16x16x32_bf16(qa0, b0, z, 0, 0, 0);
        sacc[t] = __builtin_amdgcn_mfma_f32_16x16x32_bf16(qa1, b1, z, 0, 0, 0);
    }

    // Reynolds rules + softmax per row (row = quad*4+r), P -> LDS as bf16
    float rinv[4];
    #pragma unroll
    for (int r = 0; r < 4; ++r) {
        const int row = quad*4 + r;
        const int i   = q0 + w*16 + row;
        const float mean_i = smean[w*16 + row] * 0.125f;
        float sc[5]; float mx = -3.0e38f;
        #pragma unroll
        for (int t = 0; t < 5; ++t) {
            const int jabs = j0 + w*16 + t*16 + lm;
            const int dist = i - jabs;
            float s = sacc[t][r] * 0.125f;
            const float sig = 1.f / (1.f + __expf(-s));
            float adj = s * (1.f + align) - sep * sig * sig - coh * fabsf(s - mean_i);
            const bool ok = (dist >= 0) && (dist < 64) && (jabs >= 0);
            sc[t] = ok ? adj : -3.0e38f;
            mx = fmaxf(mx, sc[t]);
        }
        mx = fmaxf(mx, __shfl_xor(mx, 1, 64));
        mx = fmaxf(mx, __shfl_xor(mx, 2, 64));
        mx = fmaxf(mx, __shfl_xor(mx, 4, 64));
        mx = fmaxf(mx, __shfl_xor(mx, 8, 64));
        float ls = 0.f;
        #pragma unroll
        for (int t = 0; t < 5; ++t) {
            const float p = __expf(sc[t] - mx);   // masked -> exp(-huge) = 0
            ls += p;
            pl[(w*16 + row) * P_STRIDE + t*16 + lm] = f2bf(p);
        }
        pl[(w*16 + row) * P_STRIDE + 80 + lm] = 0;  // zero-pad cols 80..95
        ls += __shfl_xor(ls, 1, 64);
        ls += __shfl_xor(ls, 2, 64);
        ls += __shfl_xor(ls, 4, 64);
        ls += __shfl_xor(ls, 8, 64);
        rinv[r] = 1.f / ls;
    }

    // PV: 3 ksteps x 4 d-tiles (per-wave P buffer -> no barrier needed)
    f32x4f oacc[4] = {};
    #pragma unroll
    for (int kk = 0; kk < 3; ++kk) {
        bfrag8 pa = *(const bfrag8*)&pl[(w*16 + lm) * P_STRIDE + kk*32 + quad*8];
        #pragma unroll
        for (int nt = 0; nt < 4; ++nt) {
            bfrag8 bv = *(const bfrag8*)&vst[(nt*16 + lm) * VT_STRIDE + w*16 + kk*32 + quad*8];
            oacc[nt] = __builtin_amdgcn_mfma_f32_16x16x32_bf16(pa, bv, oacc[nt], 0, 0, 0);
        }
    }

    const int b = bh >> 4, h = bh & (HEADS - 1);
    #pragma unroll
    for (int nt = 0; nt < 4; ++nt)
        #pragma unroll
        for (int r = 0; r < 4; ++r) {
            const int i = q0 + w*16 + quad*4 + r;
            const int d = nt*16 + lm;
            out[((size_t)(b * L_SEQ + i)) * DMODEL + h * HD + d] =
                f2bf(oacc[nt][r] * rinv[r]);
        }
}

extern "C" void kernel_launch(void* const* d_in, const int* in_sizes, int n_in,
                              void* d_out, int out_size, void* d_ws, size_t ws_size,
                              hipStream_t stream)
{
    (void)in_sizes; (void)n_in; (void)out_size; (void)ws_size;
    const float* x     = (const float*)d_in[0];
    const float* Wq    = (const float*)d_in[1];
    const float* Wk    = (const float*)d_in[2];
    const float* Wv    = (const float*)d_in[3];
    const float* Wo    = (const float*)d_in[4];
    const float* g_sep   = (const float*)d_in[5];
    const float* g_align = (const float*)d_in[6];
    const float* g_coh   = (const float*)d_in[7];
    float* out = (float*)d_out;

    // workspace layout (~51 MB)
    float* f = (float*)d_ws;
    float* kmean_ws = f;                              // 2048
    float* xpart_ws = kmean_ws + 2048;                // 65536
    unsigned short* xb  = (unsigned short*)(xpart_ws + 65536);
    const size_t per = (size_t)MROWS * DMODEL;        // 4 Mi
    unsigned short* wqb = xb  + per;
    unsigned short* wkb = wqb + (size_t)DMODEL*KDIM;
    unsigned short* wvb = wkb + (size_t)DMODEL*KDIM;
    unsigned short* wob = wvb + (size_t)DMODEL*KDIM;
    unsigned short* qb  = wob + (size_t)DMODEL*KDIM;
    unsigned short* kb  = qb  + per;
    unsigned short* vb  = kb  + per;
    unsigned short* attb = vb + per;

    convert_and_stats<<<dim3(64 + 4096), dim3(256), 0, stream>>>(
        x, Wq, Wk, Wv, Wo, xb, wqb, wkb, wvb, wob, xpart_ws);
    mfma_gemm<1><<<dim3(MROWS/128, 3*DMODEL/128), dim3(256), 0, stream>>>(
        xb, wqb, wkb, wvb, qb, kb, vb);
    kmean_kernel<<<dim3(BATCH*HEADS), dim3(64), 0, stream>>>(xpart_ws, Wk, kmean_ws);
    attn_kernel<<<dim3(BATCH*HEADS*(L_SEQ/QT)), dim3(256), 0, stream>>>(
        qb, kb, vb, kmean_ws, g_sep, g_align, g_coh, attb);
    mfma_gemm<0><<<dim3(MROWS/128, DMODEL/128), dim3(256), 0, stream>>>(
        attb, wob, nullptr, nullptr, out, nullptr, nullptr);
}

// Round 4
// 174.257 us; speedup vs baseline: 3.6803x; 1.1965x over previous
//
#include <hip/hip_runtime.h>
#include <math.h>

#define L_SEQ 2048
#define DMODEL 1024
#define HEADS 16
#define HD 64
#define BATCH 2
#define MROWS (BATCH*L_SEQ)   // 4096
#define KDIM 1024

typedef short bfrag8 __attribute__((ext_vector_type(8)));   // 8 bf16 = 4 VGPRs
typedef float f32x4f __attribute__((ext_vector_type(4)));

__device__ __forceinline__ unsigned short f2bf(float f) {
    unsigned u = __float_as_uint(f);
    unsigned r = u + 0x7FFFu + ((u >> 16) & 1u);   // RNE
    return (unsigned short)(r >> 16);
}
__device__ __forceinline__ float bf2f(unsigned short h) {
    return __uint_as_float(((unsigned)h) << 16);
}

// ---------------- fp32 -> bf16 convert (x + 4 weights), fully parallel -------
// 8192 blocks x 256 thr x 4 elems. blocks 0..4095: x; 4096..8191: weights.
__global__ __launch_bounds__(256) void convert_bf16(
    const float* __restrict__ x, const float* __restrict__ wq,
    const float* __restrict__ wk, const float* __restrict__ wv,
    const float* __restrict__ wo,
    unsigned short* __restrict__ xb, unsigned short* __restrict__ qwb,
    unsigned short* __restrict__ kwb, unsigned short* __restrict__ vwb,
    unsigned short* __restrict__ owb)
{
    const int bid = blockIdx.x;
    const float* src; unsigned short* dst; size_t base;
    if (bid < 4096) { src = x; dst = xb; base = (size_t)bid * 1024; }
    else {
        const int r = bid - 4096; const int w = r >> 10; const int off = r & 1023;
        src = (w==0) ? wq : (w==1) ? wk : (w==2) ? wv : wo;
        dst = (w==0) ? qwb : (w==1) ? kwb : (w==2) ? vwb : owb;
        base = (size_t)off * 1024;
    }
    const size_t idx = base + (size_t)threadIdx.x * 4;
    float4 v = *(const float4*)&src[idx];
    ushort4 o;
    o.x = f2bf(v.x); o.y = f2bf(v.y); o.z = f2bf(v.z); o.w = f2bf(v.w);
    *(ushort4*)&dst[idx] = o;
}

// ---------------- MFMA bf16 GEMM: C = A @ W^T ----------------
// MODE 1: N=3072 logical over {Wq,Wk,Wv}; head-split bf16 epilogue into C0/C1/C2
//         at [(b*H+h)*L + l]*64 + d.   MODE 0: plain fp32 (M,1024) into C0.
#define GBK 32

template<int MODE>
__global__ void mfma_gemm(
    const unsigned short* __restrict__ A,
    const unsigned short* __restrict__ W0, const unsigned short* __restrict__ W1,
    const unsigned short* __restrict__ W2,
    void* __restrict__ C0v, void* __restrict__ C1v, void* __restrict__ C2v)
{
    __shared__ short As[128*GBK];   // [row][k] row-major, NO padding (global_load_lds)
    __shared__ short Bs[128*GBK];

    const int tid  = threadIdx.x;
    const int wave = tid >> 6, lane = tid & 63;
    const int m0   = blockIdx.x * 128;
    const int n0g  = blockIdx.y * 128;

    const unsigned short* Wp; int n0; int which = 0;
    if (MODE == 1) {
        which = n0g >> 10;                      // uniform per block
        n0 = n0g & 1023;
        Wp = (which==0) ? W0 : (which==1) ? W1 : W2;
    } else { n0 = n0g; Wp = W0; }

    const int quad = lane >> 4, lm = lane & 15;
    const int wm = wave >> 1, wn = wave & 1;

    f32x4f acc[4][4] = {};

    const int ebase0 = wave * 1024;

    for (int k0 = 0; k0 < KDIM; k0 += GBK) {
        __syncthreads();
        #pragma unroll
        for (int i = 0; i < 2; ++i) {
            const int ebase = ebase0 + i * 512;
            const int e = ebase + lane * 8;
            const int row = e >> 5, col = e & 31;
            __builtin_amdgcn_global_load_lds(
                (const __attribute__((address_space(1))) void*)(A + (size_t)(m0 + row) * KDIM + k0 + col),
                (__attribute__((address_space(3))) void*)(&As[ebase]), 16, 0, 0);
            __builtin_amdgcn_global_load_lds(
                (const __attribute__((address_space(1))) void*)(Wp + (size_t)(n0 + row) * KDIM + k0 + col),
                (__attribute__((address_space(3))) void*)(&Bs[ebase]), 16, 0, 0);
        }
        __syncthreads();

        bfrag8 af[4], bf[4];
        #pragma unroll
        for (int t = 0; t < 4; ++t) {
            af[t] = *(const bfrag8*)&As[(wm*64 + t*16 + lm)*GBK + quad*8];
            bf[t] = *(const bfrag8*)&Bs[(wn*64 + t*16 + lm)*GBK + quad*8];
        }
        #pragma unroll
        for (int mt = 0; mt < 4; ++mt)
            #pragma unroll
            for (int nt = 0; nt < 4; ++nt)
                acc[mt][nt] = __builtin_amdgcn_mfma_f32_16x16x32_bf16(
                    af[mt], bf[nt], acc[mt][nt], 0, 0, 0);
    }

    // epilogue: C/D layout col=lane&15, row=quad*4+reg
    if (MODE == 1) {
        unsigned short* Cp = (unsigned short*)((which==0) ? C0v : (which==1) ? C1v : C2v);
        #pragma unroll
        for (int mt = 0; mt < 4; ++mt)
            #pragma unroll
            for (int nt = 0; nt < 4; ++nt) {
                const int gn = n0 + wn*64 + nt*16 + lm;
                const int h = gn >> 6, d = gn & 63;
                #pragma unroll
                for (int r = 0; r < 4; ++r) {
                    const int gm = m0 + wm*64 + mt*16 + quad*4 + r;
                    const int b = gm >> 11, l = gm & (L_SEQ-1);
                    Cp[(((size_t)(b*HEADS + h) * L_SEQ) + l) * HD + d] = f2bf(acc[mt][nt][r]);
                }
            }
    } else {
        float* Cp = (float*)C0v;
        #pragma unroll
        for (int mt = 0; mt < 4; ++mt)
            #pragma unroll
            for (int nt = 0; nt < 4; ++nt) {
                const int gn = n0 + wn*64 + nt*16 + lm;
                #pragma unroll
                for (int r = 0; r < 4; ++r) {
                    const int gm = m0 + wm*64 + mt*16 + quad*4 + r;
                    Cp[(size_t)gm * DMODEL + gn] = acc[mt][nt][r];
                }
            }
    }
}

// ------------- kmean[b,h,:] = mean_l k[b,h,l,:]  (k already in bf16) ---------
// 32 blocks (b,h) x 256 thr: thread (seg=t>>6, d=t&63) sums 512 rows.
__global__ __launch_bounds__(256) void kmean_from_k(
    const unsigned short* __restrict__ kb, float* __restrict__ kmean)
{
    __shared__ float part[4][64];
    const int bh = blockIdx.x, t = threadIdx.x;
    const int d = t & 63, seg = t >> 6;
    const unsigned short* kp = kb + ((size_t)bh * L_SEQ + seg * 512) * HD + d;
    float s0 = 0.f, s1 = 0.f, s2 = 0.f, s3 = 0.f;
    #pragma unroll 4
    for (int l = 0; l < 512; l += 4) {
        s0 += bf2f(kp[(size_t)(l+0) * HD]);
        s1 += bf2f(kp[(size_t)(l+1) * HD]);
        s2 += bf2f(kp[(size_t)(l+2) * HD]);
        s3 += bf2f(kp[(size_t)(l+3) * HD]);
    }
    part[seg][d] = (s0 + s1) + (s2 + s3);
    __syncthreads();
    if (t < 64)
        kmean[bh * HD + t] = (part[0][t] + part[1][t] + part[2][t] + part[3][t])
                             * (1.f / (float)L_SEQ);
}

// ---------------- MFMA windowed attention ----------------
// Block = one (b,h) x 64 queries; 4 waves x 16 queries.
#define QT 64
#define KROWS 128
#define VROWS 144
#define KS_STRIDE 72    // shorts; 144 B rows (16B-aligned), 2-way banks = free
#define VT_STRIDE 152   // shorts
#define P_STRIDE 104    // shorts

__global__ __launch_bounds__(256, 3) void attn_kernel(
    const unsigned short* __restrict__ qb, const unsigned short* __restrict__ kb,
    const unsigned short* __restrict__ vb, const float* __restrict__ kmean,
    const float* __restrict__ g_sep, const float* __restrict__ g_align,
    const float* __restrict__ g_coh, unsigned short* __restrict__ out)
{
    __shared__ unsigned short ks[KROWS * KS_STRIDE];
    __shared__ unsigned short vst[HD * VT_STRIDE];
    __shared__ unsigned short pl[QT * P_STRIDE];
    __shared__ float smean[QT];
    __shared__ float km_s[HD];

    const int tid = threadIdx.x;
    const int bh = blockIdx.x >> 5;        // L/QT = 32 tiles per (b,h)
    const int qt = blockIdx.x & 31;
    const int q0 = qt * QT;
    const int j0 = q0 - 63;

    const unsigned short* kbh = kb + (size_t)bh * L_SEQ * HD;
    const unsigned short* vbh = vb + (size_t)bh * L_SEQ * HD;

    if (tid < HD) km_s[tid] = kmean[bh * HD + tid];

    for (int idx = tid; idx < KROWS * 8; idx += 256) {
        const int r = idx & (KROWS - 1);
        const int c8 = idx >> 7;
        int j = j0 + r; j = j < 0 ? 0 : (j >= L_SEQ ? L_SEQ - 1 : j);
        bfrag8 d = *(const bfrag8*)&kbh[(size_t)j * HD + c8 * 8];
        *(bfrag8*)&ks[r * KS_STRIDE + c8 * 8] = d;
    }
    for (int idx = tid; idx < VROWS * 8; idx += 256) {
        const int r = idx % VROWS;
        const int c8 = idx / VROWS;
        int j = j0 + r; j = j < 0 ? 0 : (j >= L_SEQ ? L_SEQ - 1 : j);
        bfrag8 d = *(const bfrag8*)&vbh[(size_t)j * HD + c8 * 8];
        #pragma unroll
        for (int e = 0; e < 8; ++e)
            vst[(c8 * 8 + e) * VT_STRIDE + r] = (unsigned short)d[e];
    }

    const int w = tid >> 6, lane = tid & 63;
    const int quad = lane >> 4, lm = lane & 15;
    const float sep = g_sep[0], align = g_align[0], coh = g_coh[0];

    const unsigned short* qrow =
        qb + ((size_t)bh * L_SEQ + q0 + w*16 + lm) * HD + quad * 8;
    bfrag8 qa0 = *(const bfrag8*)qrow;
    bfrag8 qa1 = *(const bfrag8*)(qrow + 32);

    __syncthreads();

    float part = 0.f;
    #pragma unroll
    for (int j = 0; j < 8; ++j)
        part += bf2f((unsigned short)qa0[j]) * km_s[quad*8 + j]
              + bf2f((unsigned short)qa1[j]) * km_s[32 + quad*8 + j];
    part += __shfl_xor(part, 16, 64);
    part += __shfl_xor(part, 32, 64);
    if (quad == 0) smean[w*16 + lm] = part;

    f32x4f sacc[5];
    #pragma unroll
    for (int t = 0; t < 5; ++t) {
        const int krow = w*16 + t*16 + lm;
        bfrag8 b0 = *(const bfrag8*)&ks[krow * KS_STRIDE + quad*8];
        bfrag8 b1 = *(const bfrag8*)&ks[krow * KS_STRIDE + 32 + quad*8];
        f32x4f z = {0.f, 0.f, 0.f, 0.f};
        z = __builtin_amdgcn_mfma_f32_16x16x32_bf16(qa0, b0, z, 0, 0, 0);
        sacc[t] = __builtin_amdgcn_mfma_f32_16x16x32_bf16(qa1, b1, z, 0, 0, 0);
    }

    float rinv[4];
    #pragma unroll
    for (int r = 0; r < 4; ++r) {
        const int row = quad*4 + r;
        const int i   = q0 + w*16 + row;
        const float mean_i = smean[w*16 + row] * 0.125f;
        float sc[5]; float mx = -3.0e38f;
        #pragma unroll
        for (int t = 0; t < 5; ++t) {
            const int jabs = j0 + w*16 + t*16 + lm;
            const int dist = i - jabs;
            float s = sacc[t][r] * 0.125f;
            const float sig = 1.f / (1.f + __expf(-s));
            float adj = s * (1.f + align) - sep * sig * sig - coh * fabsf(s - mean_i);
            const bool ok = (dist >= 0) && (dist < 64) && (jabs >= 0);
            sc[t] = ok ? adj : -3.0e38f;
            mx = fmaxf(mx, sc[t]);
        }
        mx = fmaxf(mx, __shfl_xor(mx, 1, 64));
        mx = fmaxf(mx, __shfl_xor(mx, 2, 64));
        mx = fmaxf(mx, __shfl_xor(mx, 4, 64));
        mx = fmaxf(mx, __shfl_xor(mx, 8, 64));
        float ls = 0.f;
        #pragma unroll
        for (int t = 0; t < 5; ++t) {
            const float p = __expf(sc[t] - mx);
            ls += p;
            pl[(w*16 + row) * P_STRIDE + t*16 + lm] = f2bf(p);
        }
        pl[(w*16 + row) * P_STRIDE + 80 + lm] = 0;
        ls += __shfl_xor(ls, 1, 64);
        ls += __shfl_xor(ls, 2, 64);
        ls += __shfl_xor(ls, 4, 64);
        ls += __shfl_xor(ls, 8, 64);
        rinv[r] = 1.f / ls;
    }

    f32x4f oacc[4] = {};
    #pragma unroll
    for (int kk = 0; kk < 3; ++kk) {
        bfrag8 pa = *(const bfrag8*)&pl[(w*16 + lm) * P_STRIDE + kk*32 + quad*8];
        #pragma unroll
        for (int nt = 0; nt < 4; ++nt) {
            bfrag8 bv = *(const bfrag8*)&vst[(nt*16 + lm) * VT_STRIDE + w*16 + kk*32 + quad*8];
            oacc[nt] = __builtin_amdgcn_mfma_f32_16x16x32_bf16(pa, bv, oacc[nt], 0, 0, 0);
        }
    }

    const int b = bh >> 4, h = bh & (HEADS - 1);
    #pragma unroll
    for (int nt = 0; nt < 4; ++nt)
        #pragma unroll
        for (int r = 0; r < 4; ++r) {
            const int i = q0 + w*16 + quad*4 + r;
            const int d = nt*16 + lm;
            out[((size_t)(b * L_SEQ + i)) * DMODEL + h * HD + d] =
                f2bf(oacc[nt][r] * rinv[r]);
        }
}

extern "C" void kernel_launch(void* const* d_in, const int* in_sizes, int n_in,
                              void* d_out, int out_size, void* d_ws, size_t ws_size,
                              hipStream_t stream)
{
    (void)in_sizes; (void)n_in; (void)out_size; (void)ws_size;
    const float* x     = (const float*)d_in[0];
    const float* Wq    = (const float*)d_in[1];
    const float* Wk    = (const float*)d_in[2];
    const float* Wv    = (const float*)d_in[3];
    const float* Wo    = (const float*)d_in[4];
    const float* g_sep   = (const float*)d_in[5];
    const float* g_align = (const float*)d_in[6];
    const float* g_coh   = (const float*)d_in[7];
    float* out = (float*)d_out;

    // workspace layout (~51 MB)
    float* f = (float*)d_ws;
    float* kmean_ws = f;                              // 2048 floats
    unsigned short* xb  = (unsigned short*)(kmean_ws + 2048);
    const size_t per = (size_t)MROWS * DMODEL;        // 4 Mi
    unsigned short* wqb = xb  + per;
    unsigned short* wkb = wqb + (size_t)DMODEL*KDIM;
    unsigned short* wvb = wkb + (size_t)DMODEL*KDIM;
    unsigned short* wob = wvb + (size_t)DMODEL*KDIM;
    unsigned short* qb  = wob + (size_t)DMODEL*KDIM;
    unsigned short* kb  = qb  + per;
    unsigned short* vb  = kb  + per;
    unsigned short* attb = vb + per;

    convert_bf16<<<dim3(8192), dim3(256), 0, stream>>>(
        x, Wq, Wk, Wv, Wo, xb, wqb, wkb, wvb, wob);
    mfma_gemm<1><<<dim3(MROWS/128, 3*DMODEL/128), dim3(256), 0, stream>>>(
        xb, wqb, wkb, wvb, qb, kb, vb);
    kmean_from_k<<<dim3(BATCH*HEADS), dim3(256), 0, stream>>>(kb, kmean_ws);
    attn_kernel<<<dim3(BATCH*HEADS*(L_SEQ/QT)), dim3(256), 0, stream>>>(
        qb, kb, vb, kmean_ws, g_sep, g_align, g_coh, attb);
    mfma_gemm<0><<<dim3(MROWS/128, DMODEL/128), dim3(256), 0, stream>>>(
        attb, wob, nullptr, nullptr, out, nullptr, nullptr);
}

// Round 5
// 167.418 us; speedup vs baseline: 3.8307x; 1.0409x over previous
//
#include <hip/hip_runtime.h>
#include <math.h>

#define L_SEQ 2048
#define DMODEL 1024
#define HEADS 16
#define HD 64
#define BATCH 2
#define MROWS (BATCH*L_SEQ)   // 4096
#define KDIM 1024
#define VSTRIDE 2136          // v^T row stride (shorts): 64 front pad + 2048 + 24 tail

typedef short bfrag8 __attribute__((ext_vector_type(8)));   // 8 bf16 = 4 VGPRs
typedef float f32x4f __attribute__((ext_vector_type(4)));

__device__ __forceinline__ unsigned short f2bf(float f) {
    unsigned u = __float_as_uint(f);
    unsigned r = u + 0x7FFFu + ((u >> 16) & 1u);   // RNE
    return (unsigned short)(r >> 16);
}
__device__ __forceinline__ float bf2f(unsigned short h) {
    return __uint_as_float(((unsigned)h) << 16);
}

// ---------------- fp32 -> bf16 convert (x + 4 weights) + zero kmean_acc ------
// blocks 0..4095: x; 4096..8191: weights; 8192: zero kmean accumulator.
__global__ __launch_bounds__(256) void convert_bf16(
    const float* __restrict__ x, const float* __restrict__ wq,
    const float* __restrict__ wk, const float* __restrict__ wv,
    const float* __restrict__ wo,
    unsigned short* __restrict__ xb, unsigned short* __restrict__ qwb,
    unsigned short* __restrict__ kwb, unsigned short* __restrict__ vwb,
    unsigned short* __restrict__ owb, float* __restrict__ kmean_acc)
{
    const int bid = blockIdx.x;
    if (bid == 8192) {
        float4 z = make_float4(0.f, 0.f, 0.f, 0.f);
        *(float4*)&kmean_acc[threadIdx.x * 8]     = z;
        *(float4*)&kmean_acc[threadIdx.x * 8 + 4] = z;
        return;
    }
    const float* src; unsigned short* dst; size_t base;
    if (bid < 4096) { src = x; dst = xb; base = (size_t)bid * 1024; }
    else {
        const int r = bid - 4096; const int w = r >> 10; const int off = r & 1023;
        src = (w==0) ? wq : (w==1) ? wk : (w==2) ? wv : wo;
        dst = (w==0) ? qwb : (w==1) ? kwb : (w==2) ? vwb : owb;
        base = (size_t)off * 1024;
    }
    const size_t idx = base + (size_t)threadIdx.x * 4;
    float4 v = *(const float4*)&src[idx];
    ushort4 o;
    o.x = f2bf(v.x); o.y = f2bf(v.y); o.z = f2bf(v.z); o.w = f2bf(v.w);
    *(ushort4*)&dst[idx] = o;
}

// ---------------- MFMA bf16 GEMM: C = A @ W^T ----------------
// MODE 1: N=3072 logical over {Wq,Wk,Wv}. q,k -> bf16 head-split [b,h,l,d];
//         v -> TRANSPOSED padded [b,h,d, 64+l] (stride VSTRIDE, ushort4 stores);
//         k-blocks also atomically accumulate column sums into kmean_acc.
// MODE 0: plain fp32 (M,1024) into C0.
#define GBK 32

template<int MODE>
__global__ void mfma_gemm(
    const unsigned short* __restrict__ A,
    const unsigned short* __restrict__ W0, const unsigned short* __restrict__ W1,
    const unsigned short* __restrict__ W2,
    void* __restrict__ C0v, void* __restrict__ C1v, void* __restrict__ C2v,
    float* __restrict__ kmean_acc)
{
    __shared__ short As[128*GBK];   // [row][k] row-major, NO padding (global_load_lds)
    __shared__ short Bs[128*GBK];

    const int tid  = threadIdx.x;
    const int wave = tid >> 6, lane = tid & 63;
    const int m0   = blockIdx.x * 128;
    const int n0g  = blockIdx.y * 128;

    const unsigned short* Wp; int n0; int which = 0;
    if (MODE == 1) {
        which = n0g >> 10;                      // uniform per block
        n0 = n0g & 1023;
        Wp = (which==0) ? W0 : (which==1) ? W1 : W2;
    } else { n0 = n0g; Wp = W0; }

    const int quad = lane >> 4, lm = lane & 15;
    const int wm = wave >> 1, wn = wave & 1;

    f32x4f acc[4][4] = {};

    const int ebase0 = wave * 1024;

    for (int k0 = 0; k0 < KDIM; k0 += GBK) {
        __syncthreads();
        #pragma unroll
        for (int i = 0; i < 2; ++i) {
            const int ebase = ebase0 + i * 512;
            const int e = ebase + lane * 8;
            const int row = e >> 5, col = e & 31;
            __builtin_amdgcn_global_load_lds(
                (const __attribute__((address_space(1))) void*)(A + (size_t)(m0 + row) * KDIM + k0 + col),
                (__attribute__((address_space(3))) void*)(&As[ebase]), 16, 0, 0);
            __builtin_amdgcn_global_load_lds(
                (const __attribute__((address_space(1))) void*)(Wp + (size_t)(n0 + row) * KDIM + k0 + col),
                (__attribute__((address_space(3))) void*)(&Bs[ebase]), 16, 0, 0);
        }
        __syncthreads();

        bfrag8 af[4], bf[4];
        #pragma unroll
        for (int t = 0; t < 4; ++t) {
            af[t] = *(const bfrag8*)&As[(wm*64 + t*16 + lm)*GBK + quad*8];
            bf[t] = *(const bfrag8*)&Bs[(wn*64 + t*16 + lm)*GBK + quad*8];
        }
        #pragma unroll
        for (int mt = 0; mt < 4; ++mt)
            #pragma unroll
            for (int nt = 0; nt < 4; ++nt)
                acc[mt][nt] = __builtin_amdgcn_mfma_f32_16x16x32_bf16(
                    af[mt], bf[nt], acc[mt][nt], 0, 0, 0);
    }

    // epilogue: C/D layout col=lane&15, row=quad*4+reg
    if (MODE == 1) {
        if (which == 2) {
            // v: transposed padded layout, coalesced ushort4 (4 consecutive l)
            unsigned short* Vp = (unsigned short*)C2v;
            #pragma unroll
            for (int mt = 0; mt < 4; ++mt)
                #pragma unroll
                for (int nt = 0; nt < 4; ++nt) {
                    const int gn = n0 + wn*64 + nt*16 + lm;
                    const int h = gn >> 6, d = gn & 63;
                    const int gm0 = m0 + wm*64 + mt*16 + quad*4;
                    const int b = gm0 >> 11, l0 = gm0 & (L_SEQ-1);
                    ushort4 o;
                    o.x = f2bf(acc[mt][nt][0]); o.y = f2bf(acc[mt][nt][1]);
                    o.z = f2bf(acc[mt][nt][2]); o.w = f2bf(acc[mt][nt][3]);
                    *(ushort4*)&Vp[((size_t)((b*HEADS + h)*HD + d))*VSTRIDE + 64 + l0] = o;
                }
        } else {
            unsigned short* Cp = (unsigned short*)((which==0) ? C0v : C1v);
            #pragma unroll
            for (int mt = 0; mt < 4; ++mt)
                #pragma unroll
                for (int nt = 0; nt < 4; ++nt) {
                    const int gn = n0 + wn*64 + nt*16 + lm;
                    const int h = gn >> 6, d = gn & 63;
                    #pragma unroll
                    for (int r = 0; r < 4; ++r) {
                        const int gm = m0 + wm*64 + mt*16 + quad*4 + r;
                        const int b = gm >> 11, l = gm & (L_SEQ-1);
                        Cp[(((size_t)(b*HEADS + h) * L_SEQ) + l) * HD + d] = f2bf(acc[mt][nt][r]);
                    }
                }
            if (which == 1) {
                // kmean partial sums: one atomic per (nt) per lane
                const int b = m0 >> 11;
                #pragma unroll
                for (int nt = 0; nt < 4; ++nt) {
                    const int gn = n0 + wn*64 + nt*16 + lm;
                    const int h = gn >> 6, d = gn & 63;
                    float s = 0.f;
                    #pragma unroll
                    for (int mt = 0; mt < 4; ++mt)
                        #pragma unroll
                        for (int r = 0; r < 4; ++r) s += acc[mt][nt][r];
                    atomicAdd(&kmean_acc[(size_t)(b*HEADS + h)*HD + d], s);
                }
            }
        }
    } else {
        float* Cp = (float*)C0v;
        #pragma unroll
        for (int mt = 0; mt < 4; ++mt)
            #pragma unroll
            for (int nt = 0; nt < 4; ++nt) {
                const int gn = n0 + wn*64 + nt*16 + lm;
                #pragma unroll
                for (int r = 0; r < 4; ++r) {
                    const int gm = m0 + wm*64 + mt*16 + quad*4 + r;
                    Cp[(size_t)gm * DMODEL + gn] = acc[mt][nt][r];
                }
            }
    }
}

// ---------------- MFMA windowed attention, zero-staging ----------------
// Block = one (b,h) x 64 queries; 4 waves x 16 queries. Window base j0 = q0-64,
// 6 QK key-tiles (96 rel slots, all computed; invalid -> masked -> P=0).
// K B-frags and V^T B-frags read DIRECTLY from global (16B aligned by design).
// Only LDS: the P round-trip buffer (per-wave rows -> no barriers at all).
#define P_STRIDE 104    // shorts

__global__ __launch_bounds__(256) void attn_kernel(
    const unsigned short* __restrict__ qb, const unsigned short* __restrict__ kb,
    const unsigned short* __restrict__ vt, const float* __restrict__ kmean_acc,
    const float* __restrict__ g_sep, const float* __restrict__ g_align,
    const float* __restrict__ g_coh, unsigned short* __restrict__ out)
{
    __shared__ unsigned short pl[64 * P_STRIDE];

    const int tid = threadIdx.x;
    const int bh = blockIdx.x >> 5;        // 32 q-tiles per (b,h)
    const int qt = blockIdx.x & 31;
    const int q0 = qt * 64;
    const int j0 = q0 - 64;

    const int w = tid >> 6, lane = tid & 63;
    const int quad = lane >> 4, lm = lane & 15;
    const float sep = g_sep[0], align = g_align[0], coh = g_coh[0];

    const unsigned short* kbh = kb + (size_t)bh * L_SEQ * HD;
    const unsigned short* vbh = vt + (size_t)bh * HD * VSTRIDE;

    // Q a-frags (A[m=lm][k=quad*8+j], ksteps 0/1)
    const unsigned short* qrow =
        qb + ((size_t)bh * L_SEQ + q0 + w*16 + lm) * HD + quad * 8;
    bfrag8 qa0 = *(const bfrag8*)qrow;
    bfrag8 qa1 = *(const bfrag8*)(qrow + 32);

    // q . kmean for the cohesion mean (kmean_acc is a SUM over l; scale later)
    const float* kmp = kmean_acc + bh * HD + quad * 8;
    float4 km0 = *(const float4*)(kmp);
    float4 km1 = *(const float4*)(kmp + 4);
    float4 km2 = *(const float4*)(kmp + 32);
    float4 km3 = *(const float4*)(kmp + 36);
    float part =
        bf2f((unsigned short)qa0[0])*km0.x + bf2f((unsigned short)qa0[1])*km0.y +
        bf2f((unsigned short)qa0[2])*km0.z + bf2f((unsigned short)qa0[3])*km0.w +
        bf2f((unsigned short)qa0[4])*km1.x + bf2f((unsigned short)qa0[5])*km1.y +
        bf2f((unsigned short)qa0[6])*km1.z + bf2f((unsigned short)qa0[7])*km1.w +
        bf2f((unsigned short)qa1[0])*km2.x + bf2f((unsigned short)qa1[1])*km2.y +
        bf2f((unsigned short)qa1[2])*km2.z + bf2f((unsigned short)qa1[3])*km2.w +
        bf2f((unsigned short)qa1[4])*km3.x + bf2f((unsigned short)qa1[5])*km3.y +
        bf2f((unsigned short)qa1[6])*km3.z + bf2f((unsigned short)qa1[7])*km3.w;
    part *= (1.f / (float)L_SEQ);
    part += __shfl_xor(part, 16, 64);
    part += __shfl_xor(part, 32, 64);
    // now lane g (0..15) holds q.kmean for query w*16+g (replicated across quads)

    // QK^T: 6 tiles x 2 MFMAs, K rows direct from global (clamped; masked later)
    f32x4f sacc[6];
    #pragma unroll
    for (int t = 0; t < 6; ++t) {
        int kr = j0 + w*16 + t*16 + lm;
        kr = kr < 0 ? 0 : (kr >= L_SEQ ? L_SEQ - 1 : kr);
        const unsigned short* kp = kbh + (size_t)kr * HD + quad * 8;
        bfrag8 b0 = *(const bfrag8*)kp;
        bfrag8 b1 = *(const bfrag8*)(kp + 32);
        f32x4f z = {0.f, 0.f, 0.f, 0.f};
        z = __builtin_amdgcn_mfma_f32_16x16x32_bf16(qa0, b0, z, 0, 0, 0);
        sacc[t] = __builtin_amdgcn_mfma_f32_16x16x32_bf16(qa1, b1, z, 0, 0, 0);
    }

    // Reynolds rules + softmax per row (row = quad*4+r), P -> LDS (per-wave rows)
    float rinv[4];
    #pragma unroll
    for (int r = 0; r < 4; ++r) {
        const int row = quad*4 + r;
        const int i   = q0 + w*16 + row;
        const float mean_i = __shfl(part, row, 64) * 0.125f;
        float sc[6]; float mx = -3.0e38f;
        #pragma unroll
        for (int t = 0; t < 6; ++t) {
            const int jabs = j0 + w*16 + t*16 + lm;
            const int dist = i - jabs;
            float s = sacc[t][r] * 0.125f;
            const float sig = 1.f / (1.f + __expf(-s));
            float adj = s * (1.f + align) - sep * sig * sig - coh * fabsf(s - mean_i);
            const bool ok = (dist >= 0) && (dist < 64) && (jabs >= 0);
            sc[t] = ok ? adj : -3.0e38f;
            mx = fmaxf(mx, sc[t]);
        }
        mx = fmaxf(mx, __shfl_xor(mx, 1, 64));
        mx = fmaxf(mx, __shfl_xor(mx, 2, 64));
        mx = fmaxf(mx, __shfl_xor(mx, 4, 64));
        mx = fmaxf(mx, __shfl_xor(mx, 8, 64));
        float ls = 0.f;
        #pragma unroll
        for (int t = 0; t < 6; ++t) {
            const float p = __expf(sc[t] - mx);   // masked -> 0
            ls += p;
            pl[(w*16 + row) * P_STRIDE + t*16 + lm] = f2bf(p);
        }
        ls += __shfl_xor(ls, 1, 64);
        ls += __shfl_xor(ls, 2, 64);
        ls += __shfl_xor(ls, 4, 64);
        ls += __shfl_xor(ls, 8, 64);
        rinv[r] = 1.f / ls;
    }

    // PV: 3 ksteps x 4 d-tiles; V^T B-frags direct from global (padded rows).
    // addr offset 64 + j0 + ... = q0 + ... >= 0, 16B aligned; pad bytes are
    // finite (0xAA poison) and only ever multiply P=0.
    f32x4f oacc[4] = {};
    #pragma unroll
    for (int kk = 0; kk < 3; ++kk) {
        bfrag8 pa = *(const bfrag8*)&pl[(w*16 + lm) * P_STRIDE + kk*32 + quad*8];
        const int loff = 64 + j0 + w*16 + kk*32 + quad*8;
        #pragma unroll
        for (int nt = 0; nt < 4; ++nt) {
            bfrag8 bv = *(const bfrag8*)&vbh[(size_t)(nt*16 + lm) * VSTRIDE + loff];
            oacc[nt] = __builtin_amdgcn_mfma_f32_16x16x32_bf16(pa, bv, oacc[nt], 0, 0, 0);
        }
    }

    const int b = bh >> 4, h = bh & (HEADS - 1);
    #pragma unroll
    for (int nt = 0; nt < 4; ++nt)
        #pragma unroll
        for (int r = 0; r < 4; ++r) {
            const int i = q0 + w*16 + quad*4 + r;
            const int d = nt*16 + lm;
            out[((size_t)(b * L_SEQ + i)) * DMODEL + h * HD + d] =
                f2bf(oacc[nt][r] * rinv[r]);
        }
}

extern "C" void kernel_launch(void* const* d_in, const int* in_sizes, int n_in,
                              void* d_out, int out_size, void* d_ws, size_t ws_size,
                              hipStream_t stream)
{
    (void)in_sizes; (void)n_in; (void)out_size; (void)ws_size;
    const float* x     = (const float*)d_in[0];
    const float* Wq    = (const float*)d_in[1];
    const float* Wk    = (const float*)d_in[2];
    const float* Wv    = (const float*)d_in[3];
    const float* Wo    = (const float*)d_in[4];
    const float* g_sep   = (const float*)d_in[5];
    const float* g_align = (const float*)d_in[6];
    const float* g_coh   = (const float*)d_in[7];
    float* out = (float*)d_out;

    // workspace layout (~49 MB)
    float* kmean_ws = (float*)d_ws;                   // 2048 floats (sum, not mean)
    unsigned short* xb  = (unsigned short*)(kmean_ws + 2048);
    const size_t per = (size_t)MROWS * DMODEL;        // 4 Mi
    unsigned short* wqb = xb  + per;
    unsigned short* wkb = wqb + (size_t)DMODEL*KDIM;
    unsigned short* wvb = wkb + (size_t)DMODEL*KDIM;
    unsigned short* wob = wvb + (size_t)DMODEL*KDIM;
    unsigned short* qb  = wob + (size_t)DMODEL*KDIM;
    unsigned short* kb  = qb  + per;
    unsigned short* vtb = kb  + per;                  // [b,h,d,*] padded: 2048*VSTRIDE
    unsigned short* attb = vtb + (size_t)BATCH*HEADS*HD*VSTRIDE;

    convert_bf16<<<dim3(8193), dim3(256), 0, stream>>>(
        x, Wq, Wk, Wv, Wo, xb, wqb, wkb, wvb, wob, kmean_ws);
    mfma_gemm<1><<<dim3(MROWS/128, 3*DMODEL/128), dim3(256), 0, stream>>>(
        xb, wqb, wkb, wvb, qb, kb, vtb, kmean_ws);
    attn_kernel<<<dim3(BATCH*HEADS*(L_SEQ/64)), dim3(256), 0, stream>>>(
        qb, kb, vtb, kmean_ws, g_sep, g_align, g_coh, attb);
    mfma_gemm<0><<<dim3(MROWS/128, DMODEL/128), dim3(256), 0, stream>>>(
        attb, wob, nullptr, nullptr, out, nullptr, nullptr, nullptr);
}

// Round 6
// 163.667 us; speedup vs baseline: 3.9185x; 1.0229x over previous
//
#include <hip/hip_runtime.h>
#include <math.h>

#define L_SEQ 2048
#define DMODEL 1024
#define HEADS 16
#define HD 64
#define BATCH 2
#define MROWS (BATCH*L_SEQ)   // 4096
#define KDIM 1024
#define VSTRIDE 2136          // v^T row stride (shorts): 64 front pad + 2048 + 24 tail

typedef short bfrag8 __attribute__((ext_vector_type(8)));   // 8 bf16 = 4 VGPRs
typedef float f32x4f __attribute__((ext_vector_type(4)));

__device__ __forceinline__ unsigned short f2bf(float f) {
    unsigned u = __float_as_uint(f);
    unsigned r = u + 0x7FFFu + ((u >> 16) & 1u);   // RNE
    return (unsigned short)(r >> 16);
}
__device__ __forceinline__ float bf2f(unsigned short h) {
    return __uint_as_float(((unsigned)h) << 16);
}

// ---------------- fp32 -> bf16 convert (x + 4 weights) + zero kmean_acc ------
// blocks 0..4095: x; 4096..8191: weights; 8192: zero kmean accumulator.
__global__ __launch_bounds__(256) void convert_bf16(
    const float* __restrict__ x, const float* __restrict__ wq,
    const float* __restrict__ wk, const float* __restrict__ wv,
    const float* __restrict__ wo,
    unsigned short* __restrict__ xb, unsigned short* __restrict__ qwb,
    unsigned short* __restrict__ kwb, unsigned short* __restrict__ vwb,
    unsigned short* __restrict__ owb, float* __restrict__ kmean_acc)
{
    const int bid = blockIdx.x;
    if (bid == 8192) {
        float4 z = make_float4(0.f, 0.f, 0.f, 0.f);
        *(float4*)&kmean_acc[threadIdx.x * 8]     = z;
        *(float4*)&kmean_acc[threadIdx.x * 8 + 4] = z;
        return;
    }
    const float* src; unsigned short* dst; size_t base;
    if (bid < 4096) { src = x; dst = xb; base = (size_t)bid * 1024; }
    else {
        const int r = bid - 4096; const int w = r >> 10; const int off = r & 1023;
        src = (w==0) ? wq : (w==1) ? wk : (w==2) ? wv : wo;
        dst = (w==0) ? qwb : (w==1) ? kwb : (w==2) ? vwb : owb;
        base = (size_t)off * 1024;
    }
    const size_t idx = base + (size_t)threadIdx.x * 4;
    float4 v = *(const float4*)&src[idx];
    ushort4 o;
    o.x = f2bf(v.x); o.y = f2bf(v.y); o.z = f2bf(v.z); o.w = f2bf(v.w);
    *(ushort4*)&dst[idx] = o;
}

// ---------------- MFMA bf16 GEMM: C = A @ W^T ----------------
// BK=64, XOR-swizzled LDS (swizzle applied on the GLOBAL address per lane;
// LDS writes stay linear as global_load_lds requires). LDS k-group cg of row r
// holds global k-group cg ^ (r&7); ds_read unswizzles -> conflict-free b128.
// MODE 1: N=3072 logical over {Wq,Wk,Wv}. q,k -> bf16 head-split [b,h,l,d];
//         v -> TRANSPOSED padded [b,h,d, 64+l]; k-blocks accumulate kmean_acc.
// MODE 0: plain fp32 (M,1024) into C0.
#define GBK 64

template<int MODE>
__global__ void mfma_gemm(
    const unsigned short* __restrict__ A,
    const unsigned short* __restrict__ W0, const unsigned short* __restrict__ W1,
    const unsigned short* __restrict__ W2,
    void* __restrict__ C0v, void* __restrict__ C1v, void* __restrict__ C2v,
    float* __restrict__ kmean_acc)
{
    __shared__ short As[128*GBK];   // [row][kgroup^ (row&7)] -- swizzled
    __shared__ short Bs[128*GBK];

    const int tid  = threadIdx.x;
    const int wave = tid >> 6, lane = tid & 63;
    const int m0   = blockIdx.x * 128;
    const int n0g  = blockIdx.y * 128;

    const unsigned short* Wp; int n0; int which = 0;
    if (MODE == 1) {
        which = n0g >> 10;                      // uniform per block
        n0 = n0g & 1023;
        Wp = (which==0) ? W0 : (which==1) ? W1 : W2;
    } else { n0 = n0g; Wp = W0; }

    const int quad = lane >> 4, lm = lane & 15;
    const int wm = wave >> 1, wn = wave & 1;

    f32x4f acc[4][4] = {};

    // staging geometry: wave stages rows [wave*32, wave*32+32), 4 issues x 512 elems
    const int se   = wave * 2048 + lane * 8;   // first issue's elem for this lane
    const int srow = se >> 6;                  // row within 128
    const int scg  = (se & 63) >> 3;           // k-group 0..7
    const int sgcol = ((scg ^ (srow & 7)) << 3);

    for (int k0 = 0; k0 < KDIM; k0 += GBK) {
        __syncthreads();
        #pragma unroll
        for (int i = 0; i < 4; ++i) {
            // issue i covers elems [wave*2048 + i*512, +512): rows srow+8i
            const int ebase = wave * 2048 + i * 512;
            const int row = srow + i * 8;
            __builtin_amdgcn_global_load_lds(
                (const __attribute__((address_space(1))) void*)(A + (size_t)(m0 + row) * KDIM + k0 + sgcol),
                (__attribute__((address_space(3))) void*)(&As[ebase]), 16, 0, 0);
            __builtin_amdgcn_global_load_lds(
                (const __attribute__((address_space(1))) void*)(Wp + (size_t)(n0 + row) * KDIM + k0 + sgcol),
                (__attribute__((address_space(3))) void*)(&Bs[ebase]), 16, 0, 0);
        }
        __syncthreads();

        #pragma unroll
        for (int kk = 0; kk < 2; ++kk) {
            bfrag8 af[4], bf[4];
            #pragma unroll
            for (int t = 0; t < 4; ++t) {
                const int ar = wm*64 + t*16 + lm;
                af[t] = *(const bfrag8*)&As[ar*GBK + (((kk*4 + quad) ^ (ar & 7)) << 3)];
                const int br = wn*64 + t*16 + lm;
                bf[t] = *(const bfrag8*)&Bs[br*GBK + (((kk*4 + quad) ^ (br & 7)) << 3)];
            }
            #pragma unroll
            for (int mt = 0; mt < 4; ++mt)
                #pragma unroll
                for (int nt = 0; nt < 4; ++nt)
                    acc[mt][nt] = __builtin_amdgcn_mfma_f32_16x16x32_bf16(
                        af[mt], bf[nt], acc[mt][nt], 0, 0, 0);
        }
    }

    // epilogue: C/D layout col=lane&15, row=quad*4+reg
    if (MODE == 1) {
        if (which == 2) {
            // v: transposed padded layout, coalesced ushort4 (4 consecutive l)
            unsigned short* Vp = (unsigned short*)C2v;
            #pragma unroll
            for (int mt = 0; mt < 4; ++mt)
                #pragma unroll
                for (int nt = 0; nt < 4; ++nt) {
                    const int gn = n0 + wn*64 + nt*16 + lm;
                    const int h = gn >> 6, d = gn & 63;
                    const int gm0 = m0 + wm*64 + mt*16 + quad*4;
                    const int b = gm0 >> 11, l0 = gm0 & (L_SEQ-1);
                    ushort4 o;
                    o.x = f2bf(acc[mt][nt][0]); o.y = f2bf(acc[mt][nt][1]);
                    o.z = f2bf(acc[mt][nt][2]); o.w = f2bf(acc[mt][nt][3]);
                    *(ushort4*)&Vp[((size_t)((b*HEADS + h)*HD + d))*VSTRIDE + 64 + l0] = o;
                }
        } else {
            unsigned short* Cp = (unsigned short*)((which==0) ? C0v : C1v);
            #pragma unroll
            for (int mt = 0; mt < 4; ++mt)
                #pragma unroll
                for (int nt = 0; nt < 4; ++nt) {
                    const int gn = n0 + wn*64 + nt*16 + lm;
                    const int h = gn >> 6, d = gn & 63;
                    #pragma unroll
                    for (int r = 0; r < 4; ++r) {
                        const int gm = m0 + wm*64 + mt*16 + quad*4 + r;
                        const int b = gm >> 11, l = gm & (L_SEQ-1);
                        Cp[(((size_t)(b*HEADS + h) * L_SEQ) + l) * HD + d] = f2bf(acc[mt][nt][r]);
                    }
                }
            if (which == 1) {
                // kmean partial sums: one atomic per (nt) per lane
                const int b = m0 >> 11;
                #pragma unroll
                for (int nt = 0; nt < 4; ++nt) {
                    const int gn = n0 + wn*64 + nt*16 + lm;
                    const int h = gn >> 6, d = gn & 63;
                    float s = 0.f;
                    #pragma unroll
                    for (int mt = 0; mt < 4; ++mt)
                        #pragma unroll
                        for (int r = 0; r < 4; ++r) s += acc[mt][nt][r];
                    atomicAdd(&kmean_acc[(size_t)(b*HEADS + h)*HD + d], s);
                }
            }
        }
    } else {
        float* Cp = (float*)C0v;
        #pragma unroll
        for (int mt = 0; mt < 4; ++mt)
            #pragma unroll
            for (int nt = 0; nt < 4; ++nt) {
                const int gn = n0 + wn*64 + nt*16 + lm;
                #pragma unroll
                for (int r = 0; r < 4; ++r) {
                    const int gm = m0 + wm*64 + mt*16 + quad*4 + r;
                    Cp[(size_t)gm * DMODEL + gn] = acc[mt][nt][r];
                }
            }
    }
}

// ---------------- MFMA windowed attention, zero-staging ----------------
// Block = one (b,h) x 64 queries; 4 waves x 16 queries. Window base j0 = q0-64,
// 6 QK key-tiles (96 rel slots, all computed; invalid -> masked -> P=0).
// K B-frags and V^T B-frags read DIRECTLY from global (16B aligned by design).
// Only LDS: the P round-trip buffer (per-wave rows -> no barriers at all).
#define P_STRIDE 104    // shorts

__global__ __launch_bounds__(256) void attn_kernel(
    const unsigned short* __restrict__ qb, const unsigned short* __restrict__ kb,
    const unsigned short* __restrict__ vt, const float* __restrict__ kmean_acc,
    const float* __restrict__ g_sep, const float* __restrict__ g_align,
    const float* __restrict__ g_coh, unsigned short* __restrict__ out)
{
    __shared__ unsigned short pl[64 * P_STRIDE];

    const int tid = threadIdx.x;
    const int bh = blockIdx.x >> 5;        // 32 q-tiles per (b,h)
    const int qt = blockIdx.x & 31;
    const int q0 = qt * 64;
    const int j0 = q0 - 64;

    const int w = tid >> 6, lane = tid & 63;
    const int quad = lane >> 4, lm = lane & 15;
    const float sep = g_sep[0], align = g_align[0], coh = g_coh[0];

    const unsigned short* kbh = kb + (size_t)bh * L_SEQ * HD;
    const unsigned short* vbh = vt + (size_t)bh * HD * VSTRIDE;

    // Q a-frags (A[m=lm][k=quad*8+j], ksteps 0/1)
    const unsigned short* qrow =
        qb + ((size_t)bh * L_SEQ + q0 + w*16 + lm) * HD + quad * 8;
    bfrag8 qa0 = *(const bfrag8*)qrow;
    bfrag8 qa1 = *(const bfrag8*)(qrow + 32);

    // q . kmean for the cohesion mean (kmean_acc is a SUM over l; scale here)
    const float* kmp = kmean_acc + bh * HD + quad * 8;
    float4 km0 = *(const float4*)(kmp);
    float4 km1 = *(const float4*)(kmp + 4);
    float4 km2 = *(const float4*)(kmp + 32);
    float4 km3 = *(const float4*)(kmp + 36);
    float part =
        bf2f((unsigned short)qa0[0])*km0.x + bf2f((unsigned short)qa0[1])*km0.y +
        bf2f((unsigned short)qa0[2])*km0.z + bf2f((unsigned short)qa0[3])*km0.w +
        bf2f((unsigned short)qa0[4])*km1.x + bf2f((unsigned short)qa0[5])*km1.y +
        bf2f((unsigned short)qa0[6])*km1.z + bf2f((unsigned short)qa0[7])*km1.w +
        bf2f((unsigned short)qa1[0])*km2.x + bf2f((unsigned short)qa1[1])*km2.y +
        bf2f((unsigned short)qa1[2])*km2.z + bf2f((unsigned short)qa1[3])*km2.w +
        bf2f((unsigned short)qa1[4])*km3.x + bf2f((unsigned short)qa1[5])*km3.y +
        bf2f((unsigned short)qa1[6])*km3.z + bf2f((unsigned short)qa1[7])*km3.w;
    part *= (1.f / (float)L_SEQ);
    part += __shfl_xor(part, 16, 64);
    part += __shfl_xor(part, 32, 64);
    // lane g (0..15) holds q.kmean for query w*16+g (replicated across quads)

    // QK^T: 6 tiles x 2 MFMAs, K rows direct from global (clamped; masked later)
    f32x4f sacc[6];
    #pragma unroll
    for (int t = 0; t < 6; ++t) {
        int kr = j0 + w*16 + t*16 + lm;
        kr = kr < 0 ? 0 : (kr >= L_SEQ ? L_SEQ - 1 : kr);
        const unsigned short* kp = kbh + (size_t)kr * HD + quad * 8;
        bfrag8 b0 = *(const bfrag8*)kp;
        bfrag8 b1 = *(const bfrag8*)(kp + 32);
        f32x4f z = {0.f, 0.f, 0.f, 0.f};
        z = __builtin_amdgcn_mfma_f32_16x16x32_bf16(qa0, b0, z, 0, 0, 0);
        sacc[t] = __builtin_amdgcn_mfma_f32_16x16x32_bf16(qa1, b1, z, 0, 0, 0);
    }

    // Reynolds rules + softmax per row (row = quad*4+r), P -> LDS (per-wave rows)
    float rinv[4];
    #pragma unroll
    for (int r = 0; r < 4; ++r) {
        const int row = quad*4 + r;
        const int i   = q0 + w*16 + row;
        const float mean_i = __shfl(part, row, 64) * 0.125f;
        float sc[6]; float mx = -3.0e38f;
        #pragma unroll
        for (int t = 0; t < 6; ++t) {
            const int jabs = j0 + w*16 + t*16 + lm;
            const int dist = i - jabs;
            float s = sacc[t][r] * 0.125f;
            const float sig = 1.f / (1.f + __expf(-s));
            float adj = s * (1.f + align) - sep * sig * sig - coh * fabsf(s - mean_i);
            const bool ok = (dist >= 0) && (dist < 64) && (jabs >= 0);
            sc[t] = ok ? adj : -3.0e38f;
            mx = fmaxf(mx, sc[t]);
        }
        mx = fmaxf(mx, __shfl_xor(mx, 1, 64));
        mx = fmaxf(mx, __shfl_xor(mx, 2, 64));
        mx = fmaxf(mx, __shfl_xor(mx, 4, 64));
        mx = fmaxf(mx, __shfl_xor(mx, 8, 64));
        float ls = 0.f;
        #pragma unroll
        for (int t = 0; t < 6; ++t) {
            const float p = __expf(sc[t] - mx);   // masked -> 0
            ls += p;
            pl[(w*16 + row) * P_STRIDE + t*16 + lm] = f2bf(p);
        }
        ls += __shfl_xor(ls, 1, 64);
        ls += __shfl_xor(ls, 2, 64);
        ls += __shfl_xor(ls, 4, 64);
        ls += __shfl_xor(ls, 8, 64);
        rinv[r] = 1.f / ls;
    }

    // PV: 3 ksteps x 4 d-tiles; V^T B-frags direct from global (padded rows).
    f32x4f oacc[4] = {};
    #pragma unroll
    for (int kk = 0; kk < 3; ++kk) {
        bfrag8 pa = *(const bfrag8*)&pl[(w*16 + lm) * P_STRIDE + kk*32 + quad*8];
        const int loff = 64 + j0 + w*16 + kk*32 + quad*8;
        #pragma unroll
        for (int nt = 0; nt < 4; ++nt) {
            bfrag8 bv = *(const bfrag8*)&vbh[(size_t)(nt*16 + lm) * VSTRIDE + loff];
            oacc[nt] = __builtin_amdgcn_mfma_f32_16x16x32_bf16(pa, bv, oacc[nt], 0, 0, 0);
        }
    }

    const int b = bh >> 4, h = bh & (HEADS - 1);
    #pragma unroll
    for (int nt = 0; nt < 4; ++nt)
        #pragma unroll
        for (int r = 0; r < 4; ++r) {
            const int i = q0 + w*16 + quad*4 + r;
            const int d = nt*16 + lm;
            out[((size_t)(b * L_SEQ + i)) * DMODEL + h * HD + d] =
                f2bf(oacc[nt][r] * rinv[r]);
        }
}

extern "C" void kernel_launch(void* const* d_in, const int* in_sizes, int n_in,
                              void* d_out, int out_size, void* d_ws, size_t ws_size,
                              hipStream_t stream)
{
    (void)in_sizes; (void)n_in; (void)out_size; (void)ws_size;
    const float* x     = (const float*)d_in[0];
    const float* Wq    = (const float*)d_in[1];
    const float* Wk    = (const float*)d_in[2];
    const float* Wv    = (const float*)d_in[3];
    const float* Wo    = (const float*)d_in[4];
    const float* g_sep   = (const float*)d_in[5];
    const float* g_align = (const float*)d_in[6];
    const float* g_coh   = (const float*)d_in[7];
    float* out = (float*)d_out;

    // workspace layout (~49 MB)
    float* kmean_ws = (float*)d_ws;                   // 2048 floats (sum, not mean)
    unsigned short* xb  = (unsigned short*)(kmean_ws + 2048);
    const size_t per = (size_t)MROWS * DMODEL;        // 4 Mi
    unsigned short* wqb = xb  + per;
    unsigned short* wkb = wqb + (size_t)DMODEL*KDIM;
    unsigned short* wvb = wkb + (size_t)DMODEL*KDIM;
    unsigned short* wob = wvb + (size_t)DMODEL*KDIM;
    unsigned short* qb  = wob + (size_t)DMODEL*KDIM;
    unsigned short* kb  = qb  + per;
    unsigned short* vtb = kb  + per;                  // [b,h,d,*] padded: 2048*VSTRIDE
    unsigned short* attb = vtb + (size_t)BATCH*HEADS*HD*VSTRIDE;

    convert_bf16<<<dim3(8193), dim3(256), 0, stream>>>(
        x, Wq, Wk, Wv, Wo, xb, wqb, wkb, wvb, wob, kmean_ws);
    mfma_gemm<1><<<dim3(MROWS/128, 3*DMODEL/128), dim3(256), 0, stream>>>(
        xb, wqb, wkb, wvb, qb, kb, vtb, kmean_ws);
    attn_kernel<<<dim3(BATCH*HEADS*(L_SEQ/64)), dim3(256), 0, stream>>>(
        qb, kb, vtb, kmean_ws, g_sep, g_align, g_coh, attb);
    mfma_gemm<0><<<dim3(MROWS/128, DMODEL/128), dim3(256), 0, stream>>>(
        attb, wob, nullptr, nullptr, out, nullptr, nullptr, nullptr);
}